// Round 2
// baseline (1804.048 us; speedup 1.0000x reference)
//
#include <hip/hip_runtime.h>

// GraphNetworkMetaLayer on MI355X (gfx950).
// Edge+node models on MFMA with swapped operands: since A-frag and B-frag
// lane mappings are identical for mfma_f32_16x16x32_bf16, computing
// D^T = W^T * X^T lets each lane's X-fragment be 8 contiguous elements of
// one row -> loaded DIRECTLY from global (no LDS staging of activations).
// Software-pipelined gathers (T14): next tile's index loads issue before
// layer1, data gathers before layer2.
// d_out layout (fp32): node_out [N,32] | edge_out [E,32] | global_out [32].

#define NMAX 100000

__device__ float g_agg[NMAX * 32];   // 12.8 MB
__device__ float g_cnt[NMAX];        // 0.4 MB
__device__ float g_gsum[32];

typedef __attribute__((ext_vector_type(8))) short bf16x8;   // 8 bf16 = 4 VGPRs
typedef __attribute__((ext_vector_type(4))) float f32x4;    // MFMA C/D

// fp32 -> bf16 raw bits, round-to-nearest-even (finite inputs).
static __device__ __forceinline__ unsigned short f2us(float f) {
  union { float f; unsigned int u; } c;
  c.f = f;
  const unsigned int r = 0x7FFFu + ((c.u >> 16) & 1u);
  return (unsigned short)((c.u + r) >> 16);
}

// Swizzled LDS byte offset for a [rows][128 bf16] tile (256 B rows).
static __device__ __forceinline__ int swz(int R, int kb) {
  return (R << 8) + (kb ^ ((R & 7) << 4));
}

static __device__ __forceinline__ bf16x8 pack8(float4 a, float4 b) {
  bf16x8 u;
  u[0] = (short)f2us(a.x); u[1] = (short)f2us(a.y);
  u[2] = (short)f2us(a.z); u[3] = (short)f2us(a.w);
  u[4] = (short)f2us(b.x); u[5] = (short)f2us(b.y);
  u[6] = (short)f2us(b.z); u[7] = (short)f2us(b.w);
  return u;
}
static __device__ __forceinline__ float4 scale4(float4 a, float s) {
  return make_float4(a.x * s, a.y * s, a.z * s, a.w * s);
}

// ---------------- zero the accumulators (every call; statics persist) -------
__global__ __launch_bounds__(256) void zero_kernel() {
  const int i = blockIdx.x * 256 + threadIdx.x;
  if (i < NMAX * 32) g_agg[i] = 0.f;
  if (i < NMAX) g_cnt[i] = 0.f;
  if (i < 32) g_gsum[i] = 0.f;
}

// ---------------- edge model: MLP([x_src, x_dst, edge_attr, g]) -------------
// Persistent blocks, 4 waves x 32 edges = 128 edges/tile. No activation
// staging: A-frags gathered straight into registers. W2^T frags in VGPRs.
__global__ __launch_bounds__(256, 2) void edge_kernel(
    const float* __restrict__ x,
    const int* __restrict__ eidx,          // [2][E]: src row then dst row
    const float* __restrict__ edge_attr,
    const float* __restrict__ gattr,
    const float* __restrict__ W1,   // [128][128] (k-major)
    const float* __restrict__ b1,   // [128]
    const float* __restrict__ W2,   // [128][32]
    const float* __restrict__ b2,   // [32]
    float* __restrict__ edge_out,   // [E][32]
    const int E, const int ntiles)
{
  __shared__ short s_W1t[128 * 128];      // W1^T [n][k] bf16, swizzled: 32 KB
  __shared__ short s_h[4 * 32 * 128];     // per-wave h, swizzled:       32 KB
  __shared__ float s_b1[128];
  __shared__ float s_b2[32];

  const int t = threadIdx.x;

  // ---- one-time: stage W1^T (fp32 [k][n] -> bf16 [n][k], swizzled) ----
  {
    const float4* w1s = (const float4*)W1;   // 4096 float4
    char* b = (char*)s_W1t;
#pragma unroll
    for (int i = 0; i < 16; ++i) {
      const int idx = t + 256 * i;
      const int k = idx >> 5, n = (idx & 31) * 4;
      const float4 f = w1s[idx];
      *(short*)(b + swz(n + 0, 2 * k)) = (short)f2us(f.x);
      *(short*)(b + swz(n + 1, 2 * k)) = (short)f2us(f.y);
      *(short*)(b + swz(n + 2, 2 * k)) = (short)f2us(f.z);
      *(short*)(b + swz(n + 3, 2 * k)) = (short)f2us(f.w);
    }
    if (t < 128) s_b1[t] = b1[t];
    else if (t < 160) s_b2[t - 128] = b2[t - 128];
  }
  __syncthreads();

  const int wave = t >> 6, lane = t & 63;
  const int q = lane & 15, esub = lane >> 4;
  char* const w1b = (char*)s_W1t;
  char* const hb  = (char*)s_h;

  // ---- W2^T A-frags hoisted to registers: lane holds W2[k][ft*16+q] ----
  bf16x8 w2f[2][4];
#pragma unroll
  for (int ft = 0; ft < 2; ++ft)
#pragma unroll
    for (int kk = 0; kk < 4; ++kk) {
      const float* p = W2 + (size_t)(kk * 32 + esub * 8) * 32 + ft * 16 + q;
      bf16x8 u;
#pragma unroll
      for (int j = 0; j < 8; ++j) u[j] = (short)f2us(p[(size_t)j * 32]);
      w2f[ft][kk] = u;
    }
  const float4* gp = (const float4*)(gattr + esub * 8);
  const bf16x8 gfrag = pack8(gp[0], gp[1]);

  int tile = blockIdx.x;
  float4 buf[12];
  int d0 = 0, d1 = 0;
  {  // prologue: gathers for first tile
    const int eb = tile * 128 + wave * 32;
    const int g0 = eb + q, g1 = g0 + 16;
    const int c0 = g0 < E ? g0 : 0;
    const int c1 = g1 < E ? g1 : 0;
    const int s0 = eidx[c0]; d0 = eidx[(size_t)E + c0];
    const int s1 = eidx[c1]; d1 = eidx[(size_t)E + c1];
    const float4* p;
    p = (const float4*)(x + (size_t)s0 * 32 + esub * 8);         buf[0] = p[0];  buf[1] = p[1];
    p = (const float4*)(x + (size_t)d0 * 32 + esub * 8);         buf[2] = p[0];  buf[3] = p[1];
    p = (const float4*)(edge_attr + (size_t)c0 * 32 + esub * 8); buf[4] = p[0];  buf[5] = p[1];
    p = (const float4*)(x + (size_t)s1 * 32 + esub * 8);         buf[6] = p[0];  buf[7] = p[1];
    p = (const float4*)(x + (size_t)d1 * 32 + esub * 8);         buf[8] = p[0];  buf[9] = p[1];
    p = (const float4*)(edge_attr + (size_t)c1 * 32 + esub * 8); buf[10] = p[0]; buf[11] = p[1];
  }

  while (tile < ntiles) {
    const int ebase = tile * 128 + wave * 32;
    const bool v0 = (ebase + q) < E, v1 = (ebase + 16 + q) < E;
    const int cd0 = d0, cd1 = d1;

    // A-frags (as B operand) for both 16-edge M-tiles
    bf16x8 a0[4], a1[4];
    a0[0] = pack8(buf[0], buf[1]);  a0[1] = pack8(buf[2], buf[3]);
    a0[2] = pack8(buf[4], buf[5]);  a0[3] = gfrag;
    a1[0] = pack8(buf[6], buf[7]);  a1[1] = pack8(buf[8], buf[9]);
    a1[2] = pack8(buf[10], buf[11]); a1[3] = gfrag;

    // ---- issue next tile's index loads (hide under layer 1) ----
    const int ntile = tile + gridDim.x;
    const bool hasn = ntile < ntiles;
    int ns0 = 0, ns1 = 0;
    if (hasn) {
      const int nb = ntile * 128 + wave * 32;
      const int g0 = nb + q, g1 = g0 + 16;
      const int c0 = g0 < E ? g0 : 0;
      const int c1 = g1 < E ? g1 : 0;
      ns0 = eidx[c0]; d0 = eidx[(size_t)E + c0];
      ns1 = eidx[c1]; d1 = eidx[(size_t)E + c1];
    }

    // ---- layer 1: h^T = W1^T * e_in^T ; lane -> edge q, n=n0*16+esub*4+rr
#pragma unroll
    for (int n0 = 0; n0 < 8; ++n0) {
      const float4 bia = *(const float4*)&s_b1[n0 * 16 + esub * 4];
      f32x4 acc0 = {bia.x, bia.y, bia.z, bia.w};
      f32x4 acc1 = acc0;
#pragma unroll
      for (int kk = 0; kk < 4; ++kk) {
        const bf16x8 w = *(const bf16x8*)(w1b + swz(n0 * 16 + q, kk * 64 + esub * 16));
        acc0 = __builtin_amdgcn_mfma_f32_16x16x32_bf16(w, a0[kk], acc0, 0, 0, 0);
        acc1 = __builtin_amdgcn_mfma_f32_16x16x32_bf16(w, a1[kk], acc1, 0, 0, 0);
      }
      ushort4 h0, h1;
      h0.x = f2us(fmaxf(acc0[0], 0.f)); h0.y = f2us(fmaxf(acc0[1], 0.f));
      h0.z = f2us(fmaxf(acc0[2], 0.f)); h0.w = f2us(fmaxf(acc0[3], 0.f));
      h1.x = f2us(fmaxf(acc1[0], 0.f)); h1.y = f2us(fmaxf(acc1[1], 0.f));
      h1.z = f2us(fmaxf(acc1[2], 0.f)); h1.w = f2us(fmaxf(acc1[3], 0.f));
      *(ushort4*)(hb + swz(wave * 32 + q,      n0 * 32 + esub * 8)) = h0;
      *(ushort4*)(hb + swz(wave * 32 + 16 + q, n0 * 32 + esub * 8)) = h1;
    }

    // ---- issue next tile's data gathers (hide under layer 2) ----
    if (hasn) {
      const int nb = ntile * 128 + wave * 32;
      const int c0 = (nb + q) < E ? (nb + q) : (E - 1);
      const int c1 = (nb + 16 + q) < E ? (nb + 16 + q) : (E - 1);
      const float4* p;
      p = (const float4*)(x + (size_t)ns0 * 32 + esub * 8);        buf[0] = p[0];  buf[1] = p[1];
      p = (const float4*)(x + (size_t)d0 * 32 + esub * 8);         buf[2] = p[0];  buf[3] = p[1];
      p = (const float4*)(edge_attr + (size_t)c0 * 32 + esub * 8); buf[4] = p[0];  buf[5] = p[1];
      p = (const float4*)(x + (size_t)ns1 * 32 + esub * 8);        buf[6] = p[0];  buf[7] = p[1];
      p = (const float4*)(x + (size_t)d1 * 32 + esub * 8);         buf[8] = p[0];  buf[9] = p[1];
      p = (const float4*)(edge_attr + (size_t)c1 * 32 + esub * 8); buf[10] = p[0]; buf[11] = p[1];
    }

    // ---- layer 2: out^T = W2^T * h^T ; epilogue ----
    bf16x8 hf0[4], hf1[4];
#pragma unroll
    for (int kk = 0; kk < 4; ++kk) {
      hf0[kk] = *(const bf16x8*)(hb + swz(wave * 32 + q,      kk * 64 + esub * 16));
      hf1[kk] = *(const bf16x8*)(hb + swz(wave * 32 + 16 + q, kk * 64 + esub * 16));
    }
#pragma unroll
    for (int ft = 0; ft < 2; ++ft) {
      const float4 bia = *(const float4*)&s_b2[ft * 16 + esub * 4];
      f32x4 acc0 = {bia.x, bia.y, bia.z, bia.w};
      f32x4 acc1 = acc0;
#pragma unroll
      for (int kk = 0; kk < 4; ++kk) {
        acc0 = __builtin_amdgcn_mfma_f32_16x16x32_bf16(w2f[ft][kk], hf0[kk], acc0, 0, 0, 0);
        acc1 = __builtin_amdgcn_mfma_f32_16x16x32_bf16(w2f[ft][kk], hf1[kk], acc1, 0, 0, 0);
      }
      if (v0) {
        const int ge = ebase + q;
        *(float4*)&edge_out[(size_t)ge * 32 + ft * 16 + esub * 4] =
            make_float4(acc0[0], acc0[1], acc0[2], acc0[3]);
        float* ap = g_agg + (size_t)cd0 * 32 + ft * 16 + esub * 4;
        atomicAdd(ap + 0, acc0[0]); atomicAdd(ap + 1, acc0[1]);
        atomicAdd(ap + 2, acc0[2]); atomicAdd(ap + 3, acc0[3]);
        if (ft == 0 && esub == 0) atomicAdd(&g_cnt[cd0], 1.0f);
      }
      if (v1) {
        const int ge = ebase + 16 + q;
        *(float4*)&edge_out[(size_t)ge * 32 + ft * 16 + esub * 4] =
            make_float4(acc1[0], acc1[1], acc1[2], acc1[3]);
        float* ap = g_agg + (size_t)cd1 * 32 + ft * 16 + esub * 4;
        atomicAdd(ap + 0, acc1[0]); atomicAdd(ap + 1, acc1[1]);
        atomicAdd(ap + 2, acc1[2]); atomicAdd(ap + 3, acc1[3]);
        if (ft == 0 && esub == 0) atomicAdd(&g_cnt[cd1], 1.0f);
      }
    }
    tile = ntile;
  }
}

// ---------------- node model: MLP([x, agg, g]) + mean partials --------------
__global__ __launch_bounds__(256, 2) void node_kernel(
    const float* __restrict__ x,
    const float* __restrict__ gattr,
    const float* __restrict__ W1,   // [96][128]
    const float* __restrict__ b1,   // [128]
    const float* __restrict__ W2,   // [128][32]
    const float* __restrict__ b2,   // [32]
    float* __restrict__ node_out,   // [N][32]
    const int N, const int ntiles)
{
  __shared__ short s_W1t[128 * 128];   // only k<96 used
  __shared__ short s_h[4 * 32 * 128];
  __shared__ float s_b1[128];
  __shared__ float s_b2[32];
  __shared__ float s_gs[32];

  const int t = threadIdx.x;
  {
    const float4* w1s = (const float4*)W1;   // 3072 float4 (96x128)
    char* b = (char*)s_W1t;
#pragma unroll
    for (int i = 0; i < 12; ++i) {
      const int idx = t + 256 * i;
      const int k = idx >> 5, n = (idx & 31) * 4;
      const float4 f = w1s[idx];
      *(short*)(b + swz(n + 0, 2 * k)) = (short)f2us(f.x);
      *(short*)(b + swz(n + 1, 2 * k)) = (short)f2us(f.y);
      *(short*)(b + swz(n + 2, 2 * k)) = (short)f2us(f.z);
      *(short*)(b + swz(n + 3, 2 * k)) = (short)f2us(f.w);
    }
    if (t < 128) s_b1[t] = b1[t];
    else if (t < 160) s_b2[t - 128] = b2[t - 128];
    else if (t < 192) s_gs[t - 160] = 0.f;
  }
  __syncthreads();

  const int wave = t >> 6, lane = t & 63;
  const int q = lane & 15, esub = lane >> 4;
  char* const w1b = (char*)s_W1t;
  char* const hb  = (char*)s_h;

  bf16x8 w2f[2][4];
#pragma unroll
  for (int ft = 0; ft < 2; ++ft)
#pragma unroll
    for (int kk = 0; kk < 4; ++kk) {
      const float* p = W2 + (size_t)(kk * 32 + esub * 8) * 32 + ft * 16 + q;
      bf16x8 u;
#pragma unroll
      for (int j = 0; j < 8; ++j) u[j] = (short)f2us(p[(size_t)j * 32]);
      w2f[ft][kk] = u;
    }
  const float4* gp = (const float4*)(gattr + esub * 8);
  const bf16x8 gfrag = pack8(gp[0], gp[1]);

  f32x4 psum[2] = {{0.f, 0.f, 0.f, 0.f}, {0.f, 0.f, 0.f, 0.f}};

  int tile = blockIdx.x;
  float4 buf[8];
  float inv0 = 1.f, inv1 = 1.f;
  {
    const int nb = tile * 128 + wave * 32;
    const int c0 = (nb + q) < N ? (nb + q) : (N - 1);
    const int c1 = (nb + 16 + q) < N ? (nb + 16 + q) : (N - 1);
    const float4* p;
    p = (const float4*)(x + (size_t)c0 * 32 + esub * 8);     buf[0] = p[0]; buf[1] = p[1];
    p = (const float4*)(g_agg + (size_t)c0 * 32 + esub * 8); buf[2] = p[0]; buf[3] = p[1];
    p = (const float4*)(x + (size_t)c1 * 32 + esub * 8);     buf[4] = p[0]; buf[5] = p[1];
    p = (const float4*)(g_agg + (size_t)c1 * 32 + esub * 8); buf[6] = p[0]; buf[7] = p[1];
    inv0 = 1.0f / fmaxf(g_cnt[c0], 1.0f);
    inv1 = 1.0f / fmaxf(g_cnt[c1], 1.0f);
  }

  while (tile < ntiles) {
    const int nbase = tile * 128 + wave * 32;
    const bool v0 = (nbase + q) < N, v1 = (nbase + 16 + q) < N;

    bf16x8 a0[3], a1[3];
    a0[0] = pack8(buf[0], buf[1]);
    a0[1] = pack8(scale4(buf[2], inv0), scale4(buf[3], inv0));
    a0[2] = gfrag;
    a1[0] = pack8(buf[4], buf[5]);
    a1[1] = pack8(scale4(buf[6], inv1), scale4(buf[7], inv1));
    a1[2] = gfrag;

    const int ntile = tile + gridDim.x;
    const bool hasn = ntile < ntiles;

    // ---- layer 1 (K=96) ----
#pragma unroll
    for (int n0 = 0; n0 < 8; ++n0) {
      const float4 bia = *(const float4*)&s_b1[n0 * 16 + esub * 4];
      f32x4 acc0 = {bia.x, bia.y, bia.z, bia.w};
      f32x4 acc1 = acc0;
#pragma unroll
      for (int kk = 0; kk < 3; ++kk) {
        const bf16x8 w = *(const bf16x8*)(w1b + swz(n0 * 16 + q, kk * 64 + esub * 16));
        acc0 = __builtin_amdgcn_mfma_f32_16x16x32_bf16(w, a0[kk], acc0, 0, 0, 0);
        acc1 = __builtin_amdgcn_mfma_f32_16x16x32_bf16(w, a1[kk], acc1, 0, 0, 0);
      }
      ushort4 h0, h1;
      h0.x = f2us(fmaxf(acc0[0], 0.f)); h0.y = f2us(fmaxf(acc0[1], 0.f));
      h0.z = f2us(fmaxf(acc0[2], 0.f)); h0.w = f2us(fmaxf(acc0[3], 0.f));
      h1.x = f2us(fmaxf(acc1[0], 0.f)); h1.y = f2us(fmaxf(acc1[1], 0.f));
      h1.z = f2us(fmaxf(acc1[2], 0.f)); h1.w = f2us(fmaxf(acc1[3], 0.f));
      *(ushort4*)(hb + swz(wave * 32 + q,      n0 * 32 + esub * 8)) = h0;
      *(ushort4*)(hb + swz(wave * 32 + 16 + q, n0 * 32 + esub * 8)) = h1;
    }

    // ---- next tile loads (sequential rows; hide under layer 2) ----
    if (hasn) {
      const int nb = ntile * 128 + wave * 32;
      const int c0 = (nb + q) < N ? (nb + q) : (N - 1);
      const int c1 = (nb + 16 + q) < N ? (nb + 16 + q) : (N - 1);
      const float4* p;
      p = (const float4*)(x + (size_t)c0 * 32 + esub * 8);     buf[0] = p[0]; buf[1] = p[1];
      p = (const float4*)(g_agg + (size_t)c0 * 32 + esub * 8); buf[2] = p[0]; buf[3] = p[1];
      p = (const float4*)(x + (size_t)c1 * 32 + esub * 8);     buf[4] = p[0]; buf[5] = p[1];
      p = (const float4*)(g_agg + (size_t)c1 * 32 + esub * 8); buf[6] = p[0]; buf[7] = p[1];
      inv0 = 1.0f / fmaxf(g_cnt[c0], 1.0f);
      inv1 = 1.0f / fmaxf(g_cnt[c1], 1.0f);
    }

    // ---- layer 2 + epilogue ----
    bf16x8 hf0[4], hf1[4];
#pragma unroll
    for (int kk = 0; kk < 4; ++kk) {
      hf0[kk] = *(const bf16x8*)(hb + swz(wave * 32 + q,      kk * 64 + esub * 16));
      hf1[kk] = *(const bf16x8*)(hb + swz(wave * 32 + 16 + q, kk * 64 + esub * 16));
    }
#pragma unroll
    for (int ft = 0; ft < 2; ++ft) {
      const float4 bia = *(const float4*)&s_b2[ft * 16 + esub * 4];
      f32x4 acc0 = {bia.x, bia.y, bia.z, bia.w};
      f32x4 acc1 = acc0;
#pragma unroll
      for (int kk = 0; kk < 4; ++kk) {
        acc0 = __builtin_amdgcn_mfma_f32_16x16x32_bf16(w2f[ft][kk], hf0[kk], acc0, 0, 0, 0);
        acc1 = __builtin_amdgcn_mfma_f32_16x16x32_bf16(w2f[ft][kk], hf1[kk], acc1, 0, 0, 0);
      }
      if (v0) {
        *(float4*)&node_out[(size_t)(nbase + q) * 32 + ft * 16 + esub * 4] =
            make_float4(acc0[0], acc0[1], acc0[2], acc0[3]);
        psum[ft][0] += acc0[0]; psum[ft][1] += acc0[1];
        psum[ft][2] += acc0[2]; psum[ft][3] += acc0[3];
      }
      if (v1) {
        *(float4*)&node_out[(size_t)(nbase + 16 + q) * 32 + ft * 16 + esub * 4] =
            make_float4(acc1[0], acc1[1], acc1[2], acc1[3]);
        psum[ft][0] += acc1[0]; psum[ft][1] += acc1[1];
        psum[ft][2] += acc1[2]; psum[ft][3] += acc1[3];
      }
    }
    tile = ntile;
  }

  // ---- reduce node-mean partials: over q lanes, then LDS, then global ----
#pragma unroll
  for (int ft = 0; ft < 2; ++ft) {
    f32x4 p = psum[ft];
#pragma unroll
    for (int m = 1; m < 16; m <<= 1) {
      p[0] += __shfl_xor(p[0], m);
      p[1] += __shfl_xor(p[1], m);
      p[2] += __shfl_xor(p[2], m);
      p[3] += __shfl_xor(p[3], m);
    }
    if (q == 0) {
      atomicAdd(&s_gs[ft * 16 + esub * 4 + 0], p[0]);
      atomicAdd(&s_gs[ft * 16 + esub * 4 + 1], p[1]);
      atomicAdd(&s_gs[ft * 16 + esub * 4 + 2], p[2]);
      atomicAdd(&s_gs[ft * 16 + esub * 4 + 3], p[3]);
    }
  }
  __syncthreads();
  if (t < 32) atomicAdd(&g_gsum[t], s_gs[t]);
}

// ---------------- global model: MLP([mean(node_out), g]) --------------------
__global__ __launch_bounds__(128) void global_kernel(
    const float* __restrict__ gattr,
    const float* __restrict__ W1,   // [64][128]
    const float* __restrict__ b1,   // [128]
    const float* __restrict__ W2,   // [128][32]
    const float* __restrict__ b2,   // [32]
    float* __restrict__ gout,       // [32]
    const int N)
{
  __shared__ float s_gin[64];
  __shared__ float s_h[128];
  const int t = threadIdx.x;
  if (t < 32) s_gin[t] = g_gsum[t] / (float)N;
  else if (t < 64) s_gin[t] = gattr[t - 32];
  __syncthreads();
  {
    float a = b1[t];
#pragma unroll 4
    for (int k = 0; k < 64; ++k) a += s_gin[k] * W1[k * 128 + t];
    s_h[t] = fmaxf(a, 0.f);
  }
  __syncthreads();
  if (t < 32) {
    float o = b2[t];
#pragma unroll 4
    for (int j = 0; j < 128; ++j) o += s_h[j] * W2[j * 32 + t];
    gout[t] = o;
  }
}

extern "C" void kernel_launch(void* const* d_in, const int* in_sizes, int n_in,
                              void* d_out, int out_size, void* d_ws, size_t ws_size,
                              hipStream_t stream)
{
  const float* x         = (const float*)d_in[0];
  const int*   eidx      = (const int*)d_in[1];
  const float* edge_attr = (const float*)d_in[2];
  const float* gattr     = (const float*)d_in[3];
  const float* W1e = (const float*)d_in[4];
  const float* b1e = (const float*)d_in[5];
  const float* W2e = (const float*)d_in[6];
  const float* b2e = (const float*)d_in[7];
  const float* W1n = (const float*)d_in[8];
  const float* b1n = (const float*)d_in[9];
  const float* W2n = (const float*)d_in[10];
  const float* b2n = (const float*)d_in[11];
  const float* W1g = (const float*)d_in[12];
  const float* b1g = (const float*)d_in[13];
  const float* W2g = (const float*)d_in[14];
  const float* b2g = (const float*)d_in[15];

  const int N = in_sizes[0] / 32;
  const int E = in_sizes[2] / 32;

  float* node_out = (float*)d_out;
  float* edge_out = node_out + (size_t)N * 32;
  float* gout     = edge_out + (size_t)E * 32;

  const int etiles = (E + 127) >> 7;
  const int eblk = etiles < 512 ? etiles : 512;
  const int ntl = (N + 127) >> 7;
  const int nblk = ntl < 512 ? ntl : 512;

  zero_kernel<<<dim3((NMAX * 32 + 255) / 256), dim3(256), 0, stream>>>();
  edge_kernel<<<dim3(eblk), dim3(256), 0, stream>>>(
      x, eidx, edge_attr, gattr, W1e, b1e, W2e, b2e, edge_out, E, etiles);
  node_kernel<<<dim3(nblk), dim3(256), 0, stream>>>(
      x, gattr, W1n, b1n, W2n, b2n, node_out, N, ntl);
  global_kernel<<<dim3(1), dim3(128), 0, stream>>>(
      gattr, W1g, b1g, W2g, b2g, gout, N);
}